// Round 8
// baseline (22159.361 us; speedup 1.0000x reference)
//
#include <hip/hip_runtime.h>

// TrajectoryDecoder: 2-layer LSTM (H=256), 45 steps, B=4096.
// R8: lockstep LDS-staged weights (global_load_lds, 32KB chunks, double
// buffer), no big register arrays (kills the R4-R7 scratch-spill L2 thrash).
// BB=16, 256 WGs x 512 thr. Weights bf16 chunk-major in d_ws. Wp1 persistent
// in LDS. gctx + c-state in registers.
// mfma_f32_16x16x32_bf16: A row=lane&15(batch), k=(lane>>4)*8+j;
//   B col=lane&15(gate unit); C/D row=(lane>>4)*4+q, col=lane&15.

#define BB    16
#define TPB   512
#define HN    256
#define DM    128
#define NSTEP 45

typedef __attribute__((ext_vector_type(8))) short s8v;
typedef __attribute__((ext_vector_type(4))) float f32x4;

#define MFMA16(a,b,c) __builtin_amdgcn_mfma_f32_16x16x32_bf16((a),(b),(c),0,0,0)

__device__ __forceinline__ unsigned short f2bf(float f){
  union { float f; unsigned u; } x; x.f = f;
  unsigned r = x.u + 0x7fffu + ((x.u >> 16) & 1u);
  return (unsigned short)(r >> 16);
}
__device__ __forceinline__ float bf2f(unsigned short h){
  union { unsigned u; float f; } x; x.u = ((unsigned)h) << 16;
  return x.f;
}
__device__ __forceinline__ float sigm(float x){
  x = fminf(40.f, fmaxf(-40.f, x));
  return 1.f/(1.f + __expf(-x));
}
__device__ __forceinline__ float tanhx(float x){
  float xx = fminf(15.f, fmaxf(-15.f, x));
  float e = __expf(2.f*xx);
  return (e-1.f)/(e+1.f);
}

// h LDS: bf16 [16 rows][256], row b element u stored at u ^ ((b&7)<<3)
__device__ __forceinline__ void write_h(unsigned short* lds, int b, int u, float v){
  lds[b*HN + (u ^ ((b&7)<<3))] = f2bf(v);
}
__device__ __forceinline__ s8v read_afrag(const unsigned short* lds, int b, int hi, int kt){
  int blk = (kt*4 + hi) ^ (b & 7);
  return *(const s8v*)(lds + b*HN + blk*8);
}

// async 16KB-per-wave slice of a 32KB chunk: wave w covers [w*2048, w*2048+2048) ushorts
__device__ __forceinline__ void stage32k(const unsigned short* gsrc, unsigned short* ldst,
                                         int w, int lane){
  const unsigned short* g = gsrc + w*2048 + lane*8;
  unsigned short* l = ldst + w*2048;
  #pragma unroll
  for (int i=0;i<4;i++)
    __builtin_amdgcn_global_load_lds(
      (const __attribute__((address_space(1))) void*)(g + i*512),
      (__attribute__((address_space(3))) void*)(l + i*512), 16, 0, 0);
}

// ---- repack v2: fp32 row-major -> bf16 tiles, CHUNK-MAJOR for staging ----
// d_ws (ushort): Whh0[262144] | Wih1[262144] | Whh1[262144] | Wp1[16384]
// big matrices: tile r=(g*8+kt)*16+ut at r*512+lane*8 holds
//   W[g*256+ut*16+(lane&15)][kt*32+(lane>>4)*8+j]
// so chunk (g,kh)=32KB at (g*4+kh)*16384 is contiguous (kt=2kh,2kh+1; all ut).
// Wp1: tile r2=pt*8+kt at 786432+r2*512+lane*8, row pt*16+(lane&15).
__global__ void repack(const float* __restrict__ Whh0, const float* __restrict__ Wih1,
                       const float* __restrict__ Whh1, const float* __restrict__ Wp1,
                       unsigned short* __restrict__ dst){
  int gid  = blockIdx.x*256 + threadIdx.x;
  int lane = gid & 63;
  int tile = gid >> 6;
  const float* src; int row; size_t doff;
  int k0 = (lane>>4)*8;
  if (tile < 1536){
    int mi = tile / 512;
    int r  = tile % 512;          // (g*8+kt)*16+ut
    int ut = r & 15;
    int kt = (r >> 4) & 7;
    int g  = r >> 7;
    src  = (mi==0) ? Whh0 : (mi==1) ? Wih1 : Whh1;
    row  = g*256 + ut*16 + (lane&15);
    k0  += kt*32;
    doff = (size_t)mi*262144 + (size_t)r*512 + lane*8;
  } else {
    int r2 = tile - 1536;         // pt*8+kt
    int kt = r2 & 7, pt = r2 >> 3;
    src  = Wp1;
    row  = pt*16 + (lane&15);
    k0  += kt*32;
    doff = 786432 + (size_t)r2*512 + lane*8;
  }
  const float* s = src + (size_t)row*HN + k0;
  float4 a = *(const float4*)(s);
  float4 b = *(const float4*)(s+4);
  unsigned short* d = dst + doff;
  d[0]=f2bf(a.x); d[1]=f2bf(a.y); d[2]=f2bf(a.z); d[3]=f2bf(a.w);
  d[4]=f2bf(b.x); d[5]=f2bf(b.y); d[6]=f2bf(b.z); d[7]=f2bf(b.w);
}

__global__ __launch_bounds__(TPB, 2)
void traj_mfma(const float* __restrict__ enc,   // B x 128
               const float* __restrict__ pos0,  // B x 2
               const float* __restrict__ ctx,   // B x 128
               const float* __restrict__ Wh,    // 512 x 128
               const float* __restrict__ bh,
               const float* __restrict__ Wc,
               const float* __restrict__ bc,
               const float* __restrict__ Wih0,  // 1024 x 130
               const float* __restrict__ bih0,
               const float* __restrict__ bhh0,
               const float* __restrict__ bih1,
               const float* __restrict__ bhh1,
               const float* __restrict__ Wp2,   // 2 x 64
               const float* __restrict__ bp1,
               const float* __restrict__ bp2,
               const unsigned short* __restrict__ wsW,
               float* __restrict__ out)         // B x 45 x 2
{
  __shared__ unsigned short sh_stage[2*16384]; // 64KB double-buffer / init scratch
  __shared__ unsigned short sh_wp1[16384];     // 32KB persistent Wp1 tiles
  __shared__ unsigned short sh_h0u[BB*HN];     // 8KB bf16 swizzled
  __shared__ unsigned short sh_h1u[BB*HN];     // 8KB
  __shared__ float sh_x[BB][DM];               // 8KB staging
  __shared__ float sh_pos[BB][2];
  __shared__ float sh_red[4][BB][2];

  const int tid  = threadIdx.x;
  const int gb0  = blockIdx.x * BB;
  const int lane = tid & 63;
  const int w    = tid >> 6;        // 8 waves
  const int col  = lane & 15;
  const int hi   = lane >> 4;

  // ---- stage encoder_feat + pos ----
  {
    const float4* src = (const float4*)(enc + (size_t)gb0*DM);
    ((float4*)&sh_x[0][0])[tid] = src[tid];
  }
  if (tid < BB*2) ((float*)sh_pos)[tid] = pos0[(size_t)gb0*2 + tid];
  // persistent Wp1 -> LDS
  {
    const s8v* s = (const s8v*)(wsW + 786432);
    s8v* d = (s8v*)sh_wp1;
    #pragma unroll
    for (int i=0;i<4;i++) d[tid*4+i] = s[tid*4+i];
  }
  __syncthreads();

  // ---- h/c init: thread r computes h_all/c_all row r (fp32) ----
  {
    float* ctF = (float*)sh_stage;   // ct0 [16][256] | ct1 [16][256] (32KB)
    const int r = tid;
    float ah[BB], ac[BB];
    #pragma unroll
    for (int b=0;b<BB;b++){ ah[b]=0.f; ac[b]=0.f; }
    const float4* whr = (const float4*)(Wh + (size_t)r*DM);
    const float4* wcr = (const float4*)(Wc + (size_t)r*DM);
    #pragma nounroll
    for (int kk=0; kk<DM/4; kk++){
      float4 w0 = whr[kk], w1 = wcr[kk];
      #pragma unroll
      for (int b=0;b<BB;b++){
        float4 x = *(const float4*)&sh_x[b][kk*4];
        ah[b] += w0.x*x.x + w0.y*x.y + w0.z*x.z + w0.w*x.w;
        ac[b] += w1.x*x.x + w1.y*x.y + w1.z*x.z + w1.w*x.w;
      }
    }
    float bhv = bh[r], bcv = bc[r];
    if (r < HN){
      #pragma unroll
      for (int b=0;b<BB;b++){
        write_h(sh_h0u, b, r, ah[b] + bhv);
        ctF[(size_t)b*HN + r] = ac[b] + bcv;
      }
    } else {
      #pragma unroll
      for (int b=0;b<BB;b++){
        write_h(sh_h1u, b, r-HN, ah[b] + bhv);
        ctF[4096 + (size_t)b*HN + (r-HN)] = ac[b] + bcv;
      }
    }
  }
  __syncthreads();

  // ---- hoist c-state to regs ----
  float c0r[2][4], c1r[2][4];
  {
    const float* ctF = (const float*)sh_stage;
    #pragma unroll
    for (int m=0;m<2;m++){
      int uu = (w*2+m)*16 + col;
      #pragma unroll
      for (int q=0;q<4;q++){
        int b = hi*4+q;
        c0r[m][q] = ctF[(size_t)b*HN + uu];
        c1r[m][q] = ctF[4096 + (size_t)b*HN + uu];
      }
    }
  }
  __syncthreads();   // ct scratch free

  // ---- stage context ----
  {
    const float4* src = (const float4*)(ctx + (size_t)gb0*DM);
    ((float4*)&sh_x[0][0])[tid] = src[tid];
  }
  __syncthreads();

  // ---- gates_ctx (fp32 -> bf16 scratch): thread owns rows tid, tid+512 ----
  {
    unsigned short* gx = sh_stage;   // [16][1024] bf16 (32KB)
    float a0[BB], a1[BB];
    #pragma unroll
    for (int b=0;b<BB;b++){ a0[b]=0.f; a1[b]=0.f; }
    const float2* wr0 = (const float2*)(Wih0 + (size_t)tid*130 + 2);
    const float2* wr1 = (const float2*)(Wih0 + (size_t)(tid+512)*130 + 2);
    #pragma nounroll
    for (int kk=0; kk<DM/2; kk++){
      float2 w0 = wr0[kk], w1 = wr1[kk];
      #pragma unroll
      for (int b=0;b<BB;b++){
        float2 x = *(const float2*)&sh_x[b][kk*2];
        a0[b] += w0.x*x.x + w0.y*x.y;
        a1[b] += w1.x*x.x + w1.y*x.y;
      }
    }
    float cb0 = bih0[tid]     + bhh0[tid];
    float cb1 = bih0[tid+512] + bhh0[tid+512];
    #pragma unroll
    for (int b=0;b<BB;b++){
      gx[(size_t)b*1024 + tid]       = f2bf(a0[b] + cb0);
      gx[(size_t)b*1024 + tid + 512] = f2bf(a1[b] + cb1);
    }
  }
  __syncthreads();

  // ---- hoist gctx to regs + per-lane constants ----
  float greg[2][4][4];   // [m][g][q]
  {
    const unsigned short* gx = sh_stage;
    #pragma unroll
    for (int m=0;m<2;m++){
      int uu = (w*2+m)*16 + col;
      #pragma unroll
      for (int g=0;g<4;g++)
        #pragma unroll
        for (int q=0;q<4;q++)
          greg[m][g][q] = bf2f(gx[(size_t)(hi*4+q)*1024 + (g<<8) + uu]);
    }
  }
  float wpr[2][4][2]; float b1r[2][4];
  #pragma unroll
  for (int m=0;m<2;m++){
    int uu = (w*2+m)*16 + col;
    #pragma unroll
    for (int g=0;g<4;g++){
      int j = (g<<8) + uu;
      wpr[m][g][0] = Wih0[(size_t)j*130 + 0];
      wpr[m][g][1] = Wih0[(size_t)j*130 + 1];
      b1r[m][g]    = bih1[j] + bhh1[j];
    }
  }
  const int   p    = (w&3)*16 + col;
  const float bp1p = bp1[p], w20 = Wp2[p], w21 = Wp2[64+p];
  const float bp20 = bp2[0], bp21 = bp2[1];
  __syncthreads();   // gx scratch free -> staging buffers

  // ---- prologue: stage seq 0 (Whh0 chunk 0) into S0 ----
  stage32k(wsW, sh_stage, w, lane);
  __syncthreads();

  // ================= 45-step rollout =================
  // seq 0..15: Whh0 chunks (g=c>>2, kh=c&3); 16..31: Wih1; 32..47: Whh1; wrap->0
  #pragma nounroll
  for (int t=0; t<NSTEP; t++){
    // ---- P1: a0 frags (old h0) + pos; init layer0 acc ----
    s8v a0[8];
    #pragma unroll
    for (int kt=0;kt<8;kt++) a0[kt] = read_afrag(sh_h0u, col, hi, kt);
    float p0q[4], p1q[4];
    #pragma unroll
    for (int q=0;q<4;q++){
      float2 pp = *(const float2*)&sh_pos[hi*4+q][0];
      p0q[q]=pp.x; p1q[q]=pp.y;
    }
    f32x4 acc[2][4];
    #pragma unroll
    for (int m=0;m<2;m++)
      #pragma unroll
      for (int g=0;g<4;g++)
        #pragma unroll
        for (int q=0;q<4;q++)
          acc[m][g][q] = greg[m][g][q] + p0q[q]*wpr[m][g][0] + p1q[q]*wpr[m][g][1];

    // ---- P2: 16 Whh0 chunks ----
    #pragma nounroll
    for (int c=0;c<16;c++){
      stage32k(wsW + (size_t)(c+1)*16384, sh_stage + ((c+1)&1)*16384, w, lane);
      const unsigned short* sb = sh_stage + (c&1)*16384;
      const int g = c>>2, kh = c&3;
      #pragma unroll
      for (int ktl=0;ktl<2;ktl++)
        #pragma unroll
        for (int m=0;m<2;m++){
          s8v wf = *(const s8v*)(sb + (ktl*16 + (w*2+m))*512 + lane*8);
          acc[m][g] = MFMA16(a0[kh*2+ktl], wf, acc[m][g]);
        }
      __syncthreads();
    }

    // ---- cell0 ----
    #pragma unroll
    for (int m=0;m<2;m++){
      int uu = (w*2+m)*16 + col;
      #pragma unroll
      for (int q=0;q<4;q++){
        float iv = sigm(acc[m][0][q]), fv = sigm(acc[m][1][q]);
        float gv = tanhx(acc[m][2][q]), ov = sigm(acc[m][3][q]);
        float cv = fv*c0r[m][q] + iv*gv;
        c0r[m][q] = cv;
        write_h(sh_h0u, hi*4+q, uu, ov*tanhx(cv));
      }
    }
    __syncthreads();   // new h0 visible

    // ---- P3a: 16 Wih1 chunks (A = new h0) ----
    s8v a0n[8];
    #pragma unroll
    for (int kt=0;kt<8;kt++) a0n[kt] = read_afrag(sh_h0u, col, hi, kt);
    #pragma unroll
    for (int m=0;m<2;m++)
      #pragma unroll
      for (int g=0;g<4;g++)
        #pragma unroll
        for (int q=0;q<4;q++)
          acc[m][g][q] = b1r[m][g];
    #pragma nounroll
    for (int c=0;c<16;c++){
      const int s = 16+c;
      stage32k(wsW + (size_t)(s+1)*16384, sh_stage + ((s+1)&1)*16384, w, lane);
      const unsigned short* sb = sh_stage + (s&1)*16384;
      const int g = c>>2, kh = c&3;
      #pragma unroll
      for (int ktl=0;ktl<2;ktl++)
        #pragma unroll
        for (int m=0;m<2;m++){
          s8v wf = *(const s8v*)(sb + (ktl*16 + (w*2+m))*512 + lane*8);
          acc[m][g] = MFMA16(a0n[kh*2+ktl], wf, acc[m][g]);
        }
      __syncthreads();
    }

    // ---- P3b: 16 Whh1 chunks (A = old h1) ----
    s8v a1[8];
    #pragma unroll
    for (int kt=0;kt<8;kt++) a1[kt] = read_afrag(sh_h1u, col, hi, kt);
    #pragma nounroll
    for (int c=0;c<16;c++){
      const int s = 32+c;
      const int ns = (s+1 >= 48) ? 0 : s+1;   // wrap: prefetch next step's chunk 0
      stage32k(wsW + (size_t)ns*16384, sh_stage + ((s+1)&1)*16384, w, lane);
      const unsigned short* sb = sh_stage + (s&1)*16384;
      const int g = c>>2, kh = c&3;
      #pragma unroll
      for (int ktl=0;ktl<2;ktl++)
        #pragma unroll
        for (int m=0;m<2;m++){
          s8v wf = *(const s8v*)(sb + (ktl*16 + (w*2+m))*512 + lane*8);
          acc[m][g] = MFMA16(a1[kh*2+ktl], wf, acc[m][g]);
        }
      __syncthreads();
    }

    // ---- cell1 ----
    #pragma unroll
    for (int m=0;m<2;m++){
      int uu = (w*2+m)*16 + col;
      #pragma unroll
      for (int q=0;q<4;q++){
        float iv = sigm(acc[m][0][q]), fv = sigm(acc[m][1][q]);
        float gv = tanhx(acc[m][2][q]), ov = sigm(acc[m][3][q]);
        float cv = fv*c1r[m][q] + iv*gv;
        c1r[m][q] = cv;
        write_h(sh_h1u, hi*4+q, uu, ov*tanhx(cv));
      }
    }
    __syncthreads();   // new h1 visible

    // ---- P4: head from persistent Wp1 LDS (waves 0..3) ----
    if (w < 4){
      s8v a1n, wfp;
      f32x4 hp = {bp1p, bp1p, bp1p, bp1p};
      #pragma unroll
      for (int kt=0;kt<8;kt++){
        a1n = read_afrag(sh_h1u, col, hi, kt);
        wfp = *(const s8v*)(sh_wp1 + ((w*8+kt))*512 + lane*8);
        hp  = MFMA16(a1n, wfp, hp);
      }
      #pragma unroll
      for (int q=0;q<4;q++){
        float r  = fmaxf(hp[q], 0.f);
        float s0 = r*w20, s1 = r*w21;
        #pragma unroll
        for (int off=1; off<16; off<<=1){
          s0 += __shfl_xor(s0, off, 64);
          s1 += __shfl_xor(s1, off, 64);
        }
        if (col == 0){ sh_red[w][hi*4+q][0] = s0; sh_red[w][hi*4+q][1] = s1; }
      }
    }
    __syncthreads();

    // ---- P5: combine, update pos, write out ----
    if (tid < BB*2){
      int b = tid >> 1, d = tid & 1;
      float s = sh_red[0][b][d] + sh_red[1][b][d] + sh_red[2][b][d] + sh_red[3][b][d]
              + (d ? bp21 : bp20);
      float np = sh_pos[b][d] + s;
      sh_pos[b][d] = np;
      out[((size_t)(gb0+b)*NSTEP + t)*2 + d] = np;
    }
    __syncthreads();
  }
}

extern "C" void kernel_launch(void* const* d_in, const int* in_sizes, int n_in,
                              void* d_out, int out_size, void* d_ws, size_t ws_size,
                              hipStream_t stream) {
  const float* enc  = (const float*)d_in[0];
  const float* pos0 = (const float*)d_in[1];
  const float* ctx  = (const float*)d_in[2];
  const float* Wh   = (const float*)d_in[3];
  const float* bh   = (const float*)d_in[4];
  const float* Wc   = (const float*)d_in[5];
  const float* bc   = (const float*)d_in[6];
  const float* Wih0 = (const float*)d_in[7];
  const float* Whh0 = (const float*)d_in[8];
  const float* bih0 = (const float*)d_in[9];
  const float* bhh0 = (const float*)d_in[10];
  const float* Wih1 = (const float*)d_in[11];
  const float* Whh1 = (const float*)d_in[12];
  const float* bih1 = (const float*)d_in[13];
  const float* bhh1 = (const float*)d_in[14];
  const float* Wp1  = (const float*)d_in[15];
  const float* bp1  = (const float*)d_in[16];
  const float* Wp2  = (const float*)d_in[17];
  const float* bp2  = (const float*)d_in[18];
  float* out = (float*)d_out;
  unsigned short* wsW = (unsigned short*)d_ws;

  hipLaunchKernelGGL(repack, dim3(392), dim3(256), 0, stream,
                     Whh0, Wih1, Whh1, Wp1, wsW);

  const int B = 4096;
  hipLaunchKernelGGL(traj_mfma, dim3(B / BB), dim3(TPB), 0, stream,
                     enc, pos0, ctx, Wh, bh, Wc, bc, Wih0, bih0, bhh0,
                     bih1, bhh1, Wp2, bp1, bp2, wsW, out);
}

// Round 9
// 5081.731 us; speedup vs baseline: 4.3606x; 4.3606x over previous
//
#include <hip/hip_runtime.h>

// TrajectoryDecoder: 2-layer LSTM (H=256), 45 steps, B=4096.
// R9: spill-free MFMA rollout. BB=16, 256 WGs x 512 thr (8 waves).
// Weights bf16 B-frag tiles in d_ws (R5 layout), loaded global->VGPR
// per fragment (coalesced dwordx4, L2-resident). A-frags ds_read per kt
// (no register arrays). gctx bf16 persistent in LDS. ALL loop indices
// compile-time (rule #20). Per-thread state ~70 VGPR + 32 AGPR acc.
// mfma_f32_16x16x32_bf16: A row=lane&15(batch), k=(lane>>4)*8+j;
//   B col=lane&15(gate unit); C/D row=(lane>>4)*4+q, col=lane&15.

#define BB    16
#define TPB   512
#define HN    256
#define DM    128
#define NSTEP 45

typedef __attribute__((ext_vector_type(8))) short s8v;
typedef __attribute__((ext_vector_type(4))) float f32x4;

#define MFMA16(a,b,c) __builtin_amdgcn_mfma_f32_16x16x32_bf16((a),(b),(c),0,0,0)

__device__ __forceinline__ unsigned short f2bf(float f){
  union { float f; unsigned u; } x; x.f = f;
  unsigned r = x.u + 0x7fffu + ((x.u >> 16) & 1u);
  return (unsigned short)(r >> 16);
}
__device__ __forceinline__ float bf2f(unsigned short h){
  union { unsigned u; float f; } x; x.u = ((unsigned)h) << 16;
  return x.f;
}
__device__ __forceinline__ float sigm(float x){
  x = fminf(40.f, fmaxf(-40.f, x));
  return 1.f/(1.f + __expf(-x));
}
__device__ __forceinline__ float tanhx(float x){
  float xx = fminf(15.f, fmaxf(-15.f, x));
  float e = __expf(2.f*xx);
  return (e-1.f)/(e+1.f);
}

// h LDS: bf16 [16 rows][256], row b element u stored at u ^ ((b&7)<<3)
__device__ __forceinline__ void write_h(unsigned short* lds, int b, int u, float v){
  lds[b*HN + (u ^ ((b&7)<<3))] = f2bf(v);
}
__device__ __forceinline__ s8v read_afrag(const unsigned short* lds, int b, int hi, int kt){
  int blk = (kt*4 + hi) ^ (b & 7);
  return *(const s8v*)(lds + b*HN + blk*8);
}

// ---- repack: fp32 row-major -> bf16 B-fragment tiles (R5 layout) ----
// d_ws (ushort): Whh0[262144] | Wih1[262144] | Whh1[262144] | Wp1[16384]
// tile r=(ut*4+g)*8+kt at r*512+lane*8 holds W[g*256+ut*16+(lane&15)][kt*32+(lane>>4)*8+j]
__global__ void repack(const float* __restrict__ Whh0, const float* __restrict__ Wih1,
                       const float* __restrict__ Whh1, const float* __restrict__ Wp1,
                       unsigned short* __restrict__ dst){
  int gid  = blockIdx.x*256 + threadIdx.x;
  int lane = gid & 63;
  int tile = gid >> 6;
  const float* src; int row; size_t doff;
  int k0 = (lane>>4)*8;
  if (tile < 1536){
    int mi = tile / 512;
    int r  = tile % 512;
    int kt = r & 7;
    int gu = r >> 3;
    int g  = gu & 3, ut = gu >> 2;
    src  = (mi==0) ? Whh0 : (mi==1) ? Wih1 : Whh1;
    row  = g*256 + ut*16 + (lane&15);
    k0  += kt*32;
    doff = (size_t)mi*262144 + (size_t)r*512 + lane*8;
  } else {
    int r2 = tile - 1536;         // pt*8+kt
    int kt = r2 & 7, pt = r2 >> 3;
    src  = Wp1;
    row  = pt*16 + (lane&15);
    k0  += kt*32;
    doff = 786432 + (size_t)r2*512 + lane*8;
  }
  const float* s = src + (size_t)row*HN + k0;
  float4 a = *(const float4*)(s);
  float4 b = *(const float4*)(s+4);
  unsigned short* d = dst + doff;
  d[0]=f2bf(a.x); d[1]=f2bf(a.y); d[2]=f2bf(a.z); d[3]=f2bf(a.w);
  d[4]=f2bf(b.x); d[5]=f2bf(b.y); d[6]=f2bf(b.z); d[7]=f2bf(b.w);
}

__global__ __launch_bounds__(TPB, 1)
void traj_mfma(const float* __restrict__ enc,   // B x 128
               const float* __restrict__ pos0,  // B x 2
               const float* __restrict__ ctx,   // B x 128
               const float* __restrict__ Wh,    // 512 x 128
               const float* __restrict__ bh,
               const float* __restrict__ Wc,
               const float* __restrict__ bc,
               const float* __restrict__ Wih0,  // 1024 x 130
               const float* __restrict__ bih0,
               const float* __restrict__ bhh0,
               const float* __restrict__ bih1,
               const float* __restrict__ bhh1,
               const float* __restrict__ Wp2,   // 2 x 64
               const float* __restrict__ bp1,
               const float* __restrict__ bp2,
               const unsigned short* __restrict__ wsW,
               float* __restrict__ out)         // B x 45 x 2
{
  __shared__ unsigned short sh_gx[BB*1024];    // 32KB: ct fp32 (init) then gctx bf16
  __shared__ unsigned short sh_h0u[BB*HN];     // 8KB bf16 swizzled
  __shared__ unsigned short sh_h1u[BB*HN];     // 8KB
  __shared__ float sh_x[BB][DM];               // 8KB staging
  __shared__ float sh_pos[BB][2];
  __shared__ float sh_red[4][BB][2];

  const int tid  = threadIdx.x;
  const int gb0  = blockIdx.x * BB;
  const int lane = tid & 63;
  const int w    = tid >> 6;        // 8 waves
  const int col  = lane & 15;
  const int hi   = lane >> 4;

  // ---- stage encoder_feat + pos ----
  {
    const float4* src = (const float4*)(enc + (size_t)gb0*DM);
    ((float4*)&sh_x[0][0])[tid] = src[tid];
  }
  if (tid < BB*2) ((float*)sh_pos)[tid] = pos0[(size_t)gb0*2 + tid];
  __syncthreads();

  // ---- h/c init: thread r computes h_all/c_all row r (fp32) ----
  {
    float* ctF = (float*)sh_gx;   // ct0 [16][256] | ct1 [16][256] (32KB)
    const int r = tid;
    float ah[BB], ac[BB];
    #pragma unroll
    for (int b=0;b<BB;b++){ ah[b]=0.f; ac[b]=0.f; }
    const float4* whr = (const float4*)(Wh + (size_t)r*DM);
    const float4* wcr = (const float4*)(Wc + (size_t)r*DM);
    #pragma nounroll
    for (int kk=0; kk<DM/4; kk++){
      float4 w0 = whr[kk], w1 = wcr[kk];
      #pragma unroll
      for (int b=0;b<BB;b++){
        float4 x = *(const float4*)&sh_x[b][kk*4];
        ah[b] += w0.x*x.x + w0.y*x.y + w0.z*x.z + w0.w*x.w;
        ac[b] += w1.x*x.x + w1.y*x.y + w1.z*x.z + w1.w*x.w;
      }
    }
    float bhv = bh[r], bcv = bc[r];
    if (r < HN){
      #pragma unroll
      for (int b=0;b<BB;b++){
        write_h(sh_h0u, b, r, ah[b] + bhv);
        ctF[(size_t)b*HN + r] = ac[b] + bcv;
      }
    } else {
      #pragma unroll
      for (int b=0;b<BB;b++){
        write_h(sh_h1u, b, r-HN, ah[b] + bhv);
        ctF[4096 + (size_t)b*HN + (r-HN)] = ac[b] + bcv;
      }
    }
  }
  __syncthreads();

  // ---- hoist c-state to regs (static indices) ----
  float c0r[2][4], c1r[2][4];
  {
    const float* ctF = (const float*)sh_gx;
    #pragma unroll
    for (int m=0;m<2;m++){
      int uu = (w*2+m)*16 + col;
      #pragma unroll
      for (int q=0;q<4;q++){
        int b = hi*4+q;
        c0r[m][q] = ctF[(size_t)b*HN + uu];
        c1r[m][q] = ctF[4096 + (size_t)b*HN + uu];
      }
    }
  }
  __syncthreads();   // ct region free

  // ---- stage context ----
  {
    const float4* src = (const float4*)(ctx + (size_t)gb0*DM);
    ((float4*)&sh_x[0][0])[tid] = src[tid];
  }
  __syncthreads();

  // ---- gates_ctx -> bf16 LDS [16][1024] (persistent) ----
  {
    float a0[BB], a1[BB];
    #pragma unroll
    for (int b=0;b<BB;b++){ a0[b]=0.f; a1[b]=0.f; }
    const float2* wr0 = (const float2*)(Wih0 + (size_t)tid*130 + 2);
    const float2* wr1 = (const float2*)(Wih0 + (size_t)(tid+512)*130 + 2);
    #pragma nounroll
    for (int kk=0; kk<DM/2; kk++){
      float2 w0 = wr0[kk], w1 = wr1[kk];
      #pragma unroll
      for (int b=0;b<BB;b++){
        float2 x = *(const float2*)&sh_x[b][kk*2];
        a0[b] += w0.x*x.x + w0.y*x.y;
        a1[b] += w1.x*x.x + w1.y*x.y;
      }
    }
    float cb0 = bih0[tid]     + bhh0[tid];
    float cb1 = bih0[tid+512] + bhh0[tid+512];
    #pragma unroll
    for (int b=0;b<BB;b++){
      sh_gx[(size_t)b*1024 + tid]       = f2bf(a0[b] + cb0);
      sh_gx[(size_t)b*1024 + tid + 512] = f2bf(a1[b] + cb1);
    }
  }

  // ---- per-lane constants ----
  float wpr[2][4][2]; float b1r[2][4];
  #pragma unroll
  for (int m=0;m<2;m++){
    int uu = (w*2+m)*16 + col;
    #pragma unroll
    for (int g=0;g<4;g++){
      int j = (g<<8) + uu;
      wpr[m][g][0] = Wih0[(size_t)j*130 + 0];
      wpr[m][g][1] = Wih0[(size_t)j*130 + 1];
      b1r[m][g]    = bih1[j] + bhh1[j];
    }
  }
  const int   p    = (w&3)*16 + col;
  const float bp1p = bp1[p], w20 = Wp2[p], w21 = Wp2[64+p];
  const float bp20 = bp2[0], bp21 = bp2[1];

  // per-wave weight tile bases (ushort units), R5 layout
  const unsigned short* wT0 = wsW            + lane*8;  // Whh0
  const unsigned short* wT1 = wsW + 262144   + lane*8;  // Wih1
  const unsigned short* wT2 = wsW + 524288   + lane*8;  // Whh1
  const unsigned short* wTp = wsW + 786432   + lane*8;  // Wp1
  __syncthreads();   // gctx visible

  // ================= 45-step rollout =================
  #pragma nounroll
  for (int t=0; t<NSTEP; t++){
    // ---- P1+P2: layer0 gates (acc init from gctx LDS + pos) ----
    f32x4 acc[2][4];
    #pragma unroll
    for (int m=0;m<2;m++){
      const int uu = (w*2+m)*16 + col;
      #pragma unroll
      for (int q=0;q<4;q++){
        float2 pp = *(const float2*)&sh_pos[hi*4+q][0];
        #pragma unroll
        for (int g=0;g<4;g++)
          acc[m][g][q] = bf2f(sh_gx[(size_t)(hi*4+q)*1024 + (g<<8) + uu])
                       + pp.x*wpr[m][g][0] + pp.y*wpr[m][g][1];
      }
    }
    #pragma unroll
    for (int kt=0;kt<8;kt++){
      s8v a0 = read_afrag(sh_h0u, col, hi, kt);
      #pragma unroll
      for (int m=0;m<2;m++){
        const int ut = w*2+m;
        #pragma unroll
        for (int g=0;g<4;g++){
          s8v wf = *(const s8v*)(wT0 + (size_t)((ut*4+g)*8+kt)*512);
          acc[m][g] = MFMA16(a0, wf, acc[m][g]);
        }
      }
    }
    __syncthreads();   // all reads of old h0 / pos done

    // ---- cell0 ----
    #pragma unroll
    for (int m=0;m<2;m++){
      int uu = (w*2+m)*16 + col;
      #pragma unroll
      for (int q=0;q<4;q++){
        float iv = sigm(acc[m][0][q]), fv = sigm(acc[m][1][q]);
        float gv = tanhx(acc[m][2][q]), ov = sigm(acc[m][3][q]);
        float cv = fv*c0r[m][q] + iv*gv;
        c0r[m][q] = cv;
        write_h(sh_h0u, hi*4+q, uu, ov*tanhx(cv));
      }
    }
    __syncthreads();   // new h0 visible

    // ---- layer1 gates: Wih1 @ h0new + Whh1 @ h1old ----
    #pragma unroll
    for (int m=0;m<2;m++)
      #pragma unroll
      for (int g=0;g<4;g++)
        #pragma unroll
        for (int q=0;q<4;q++)
          acc[m][g][q] = b1r[m][g];
    #pragma unroll
    for (int kt=0;kt<8;kt++){
      s8v a0n = read_afrag(sh_h0u, col, hi, kt);
      #pragma unroll
      for (int m=0;m<2;m++){
        const int ut = w*2+m;
        #pragma unroll
        for (int g=0;g<4;g++){
          s8v wf = *(const s8v*)(wT1 + (size_t)((ut*4+g)*8+kt)*512);
          acc[m][g] = MFMA16(a0n, wf, acc[m][g]);
        }
      }
    }
    #pragma unroll
    for (int kt=0;kt<8;kt++){
      s8v a1 = read_afrag(sh_h1u, col, hi, kt);
      #pragma unroll
      for (int m=0;m<2;m++){
        const int ut = w*2+m;
        #pragma unroll
        for (int g=0;g<4;g++){
          s8v wf = *(const s8v*)(wT2 + (size_t)((ut*4+g)*8+kt)*512);
          acc[m][g] = MFMA16(a1, wf, acc[m][g]);
        }
      }
    }
    __syncthreads();   // all reads of old h1 done

    // ---- cell1 ----
    #pragma unroll
    for (int m=0;m<2;m++){
      int uu = (w*2+m)*16 + col;
      #pragma unroll
      for (int q=0;q<4;q++){
        float iv = sigm(acc[m][0][q]), fv = sigm(acc[m][1][q]);
        float gv = tanhx(acc[m][2][q]), ov = sigm(acc[m][3][q]);
        float cv = fv*c1r[m][q] + iv*gv;
        c1r[m][q] = cv;
        write_h(sh_h1u, hi*4+q, uu, ov*tanhx(cv));
      }
    }
    __syncthreads();   // new h1 visible

    // ---- head (waves 0..3; p-unit = (w&3)*16+col) ----
    if (w < 4){
      f32x4 hp = {bp1p, bp1p, bp1p, bp1p};
      #pragma unroll
      for (int kt=0;kt<8;kt++){
        s8v a1n = read_afrag(sh_h1u, col, hi, kt);
        s8v wfp = *(const s8v*)(wTp + (size_t)((w&3)*8+kt)*512);
        hp = MFMA16(a1n, wfp, hp);
      }
      #pragma unroll
      for (int q=0;q<4;q++){
        float r  = fmaxf(hp[q], 0.f);
        float s0 = r*w20, s1 = r*w21;
        #pragma unroll
        for (int off=1; off<16; off<<=1){
          s0 += __shfl_xor(s0, off, 64);
          s1 += __shfl_xor(s1, off, 64);
        }
        if (col == 0){ sh_red[w][hi*4+q][0] = s0; sh_red[w][hi*4+q][1] = s1; }
      }
    }
    __syncthreads();   // sh_red complete

    // ---- P5: combine, update pos, write out ----
    if (tid < BB*2){
      int b = tid >> 1, d = tid & 1;
      float s = sh_red[0][b][d] + sh_red[1][b][d] + sh_red[2][b][d] + sh_red[3][b][d]
              + (d ? bp21 : bp20);
      float np = sh_pos[b][d] + s;
      sh_pos[b][d] = np;
      out[((size_t)(gb0+b)*NSTEP + t)*2 + d] = np;
    }
    __syncthreads();   // pos stable for next step
  }
}

extern "C" void kernel_launch(void* const* d_in, const int* in_sizes, int n_in,
                              void* d_out, int out_size, void* d_ws, size_t ws_size,
                              hipStream_t stream) {
  const float* enc  = (const float*)d_in[0];
  const float* pos0 = (const float*)d_in[1];
  const float* ctx  = (const float*)d_in[2];
  const float* Wh   = (const float*)d_in[3];
  const float* bh   = (const float*)d_in[4];
  const float* Wc   = (const float*)d_in[5];
  const float* bc   = (const float*)d_in[6];
  const float* Wih0 = (const float*)d_in[7];
  const float* Whh0 = (const float*)d_in[8];
  const float* bih0 = (const float*)d_in[9];
  const float* bhh0 = (const float*)d_in[10];
  const float* Wih1 = (const float*)d_in[11];
  const float* Whh1 = (const float*)d_in[12];
  const float* bih1 = (const float*)d_in[13];
  const float* bhh1 = (const float*)d_in[14];
  const float* Wp1  = (const float*)d_in[15];
  const float* bp1  = (const float*)d_in[16];
  const float* Wp2  = (const float*)d_in[17];
  const float* bp2  = (const float*)d_in[18];
  float* out = (float*)d_out;
  unsigned short* wsW = (unsigned short*)d_ws;

  hipLaunchKernelGGL(repack, dim3(392), dim3(256), 0, stream,
                     Whh0, Wih1, Whh1, Wp1, wsW);

  const int B = 4096;
  hipLaunchKernelGGL(traj_mfma, dim3(B / BB), dim3(TPB), 0, stream,
                     enc, pos0, ctx, Wh, bh, Wc, bc, Wih0, bih0, bhh0,
                     bih1, bhh1, Wp2, bp1, bp2, wsW, out);
}

// Round 10
// 3573.697 us; speedup vs baseline: 6.2007x; 1.4220x over previous
//
#include <hip/hip_runtime.h>

// TrajectoryDecoder: 2-layer LSTM (H=256), 45 steps, B=4096.
// R10: R8's lockstep global_load_lds chunk sweep (48 x 32KB/step, 3-buffer
// rotation, counted vmcnt(4) + raw s_barrier, stage 2-deep) combined with
// R9's fully-static indexing (no runtime-indexed ext_vector arrays).
// BB=16, 256 WGs x 512 thr (8 waves). Weights bf16 chunk-major in d_ws.
// mfma_f32_16x16x32_bf16: A row=lane&15(batch), k=(lane>>4)*8+j;
//   B col=lane&15(gate unit); C/D row=(lane>>4)*4+q, col=lane&15.

#define BB    16
#define TPB   512
#define HN    256
#define DM    128
#define NSTEP 45

typedef __attribute__((ext_vector_type(8))) short s8v;
typedef __attribute__((ext_vector_type(4))) float f32x4;

#define MFMA16(a,b,c) __builtin_amdgcn_mfma_f32_16x16x32_bf16((a),(b),(c),0,0,0)

__device__ __forceinline__ unsigned short f2bf(float f){
  union { float f; unsigned u; } x; x.f = f;
  unsigned r = x.u + 0x7fffu + ((x.u >> 16) & 1u);
  return (unsigned short)(r >> 16);
}
__device__ __forceinline__ float bf2f(unsigned short h){
  union { unsigned u; float f; } x; x.u = ((unsigned)h) << 16;
  return x.f;
}
__device__ __forceinline__ float sigm(float x){
  x = fminf(40.f, fmaxf(-40.f, x));
  return 1.f/(1.f + __expf(-x));
}
__device__ __forceinline__ float tanhx(float x){
  float xx = fminf(15.f, fmaxf(-15.f, x));
  float e = __expf(2.f*xx);
  return (e-1.f)/(e+1.f);
}

// h LDS: bf16 [16 rows][256], row b element u stored at u ^ ((b&7)<<3)
__device__ __forceinline__ void write_h(unsigned short* lds, int b, int u, float v){
  lds[b*HN + (u ^ ((b&7)<<3))] = f2bf(v);
}
__device__ __forceinline__ s8v read_afrag(const unsigned short* lds, int b, int hi, int kt){
  int blk = (kt*4 + hi) ^ (b & 7);
  return *(const s8v*)(lds + b*HN + blk*8);
}

// ---- repack v2 (R8 layout): fp32 row-major -> bf16 tiles, CHUNK-MAJOR ----
// d_ws (ushort): Whh0[262144] | Wih1[262144] | Whh1[262144] | Wp1[16384]
// big matrices: tile r=(g*8+kt)*16+ut at mi*262144 + r*512 + lane*8 holds
//   W[g*256+ut*16+(lane&15)][kt*32+(lane>>4)*8+j]
// chunk (g,kh)=32KB at (g*4+kh)*16384 contiguous (kt=2kh,2kh+1; all ut).
// Wp1: tile r2=pt*8+kt at 786432+r2*512+lane*8, row pt*16+(lane&15).
__global__ void repack(const float* __restrict__ Whh0, const float* __restrict__ Wih1,
                       const float* __restrict__ Whh1, const float* __restrict__ Wp1,
                       unsigned short* __restrict__ dst){
  int gid  = blockIdx.x*256 + threadIdx.x;
  int lane = gid & 63;
  int tile = gid >> 6;
  const float* src; int row; size_t doff;
  int k0 = (lane>>4)*8;
  if (tile < 1536){
    int mi = tile / 512;
    int r  = tile % 512;          // (g*8+kt)*16+ut
    int ut = r & 15;
    int kt = (r >> 4) & 7;
    int g  = r >> 7;
    src  = (mi==0) ? Whh0 : (mi==1) ? Wih1 : Whh1;
    row  = g*256 + ut*16 + (lane&15);
    k0  += kt*32;
    doff = (size_t)mi*262144 + (size_t)r*512 + lane*8;
  } else {
    int r2 = tile - 1536;         // pt*8+kt
    int kt = r2 & 7, pt = r2 >> 3;
    src  = Wp1;
    row  = pt*16 + (lane&15);
    k0  += kt*32;
    doff = 786432 + (size_t)r2*512 + lane*8;
  }
  const float* s = src + (size_t)row*HN + k0;
  float4 a = *(const float4*)(s);
  float4 b = *(const float4*)(s+4);
  unsigned short* d = dst + doff;
  d[0]=f2bf(a.x); d[1]=f2bf(a.y); d[2]=f2bf(a.z); d[3]=f2bf(a.w);
  d[4]=f2bf(b.x); d[5]=f2bf(b.y); d[6]=f2bf(b.z); d[7]=f2bf(b.w);
}

// stage one 32KB chunk: wave w covers [w*2048, w*2048+2048) ushorts, 4 loads
#define STAGE(seq, bufi) do{ \
  const unsigned short* g_ = wsW + (size_t)(seq)*16384 + w*2048 + lane*8; \
  unsigned short* l_ = sh_stage + (bufi)*16384 + w*2048; \
  __builtin_amdgcn_global_load_lds((const __attribute__((address_space(1))) void*)(g_       ), (__attribute__((address_space(3))) void*)(l_       ), 16,0,0); \
  __builtin_amdgcn_global_load_lds((const __attribute__((address_space(1))) void*)(g_ +  512), (__attribute__((address_space(3))) void*)(l_ +  512), 16,0,0); \
  __builtin_amdgcn_global_load_lds((const __attribute__((address_space(1))) void*)(g_ + 1024), (__attribute__((address_space(3))) void*)(l_ + 1024), 16,0,0); \
  __builtin_amdgcn_global_load_lds((const __attribute__((address_space(1))) void*)(g_ + 1536), (__attribute__((address_space(3))) void*)(l_ + 1536), 16,0,0); \
}while(0)

// one chunk: wait own seq-c loads, barrier, prefetch seq c+2 (wrap 48), 4 MFMAs
// cl: 0..15 literal after unroll; MI: 0/1/2; HS: h LDS source for A-frags
#define CHUNK(cl, MI, HS) do{ \
  const int c_  = (MI)*16 + (cl); \
  const int s2_ = (c_+2) % 48; \
  asm volatile("s_waitcnt vmcnt(4)" ::: "memory"); \
  __builtin_amdgcn_s_barrier(); \
  __builtin_amdgcn_sched_barrier(0); \
  STAGE(s2_, (c_+2)%3); \
  const unsigned short* sb_ = sh_stage + (c_%3)*16384 + lane*8; \
  const int gI_ = (cl)>>2, kh_ = (cl)&3; \
  s8v aA_ = read_afrag(HS, col, hi, 2*kh_+0); \
  s8v aB_ = read_afrag(HS, col, hi, 2*kh_+1); \
  { s8v wf_ = *(const s8v*)(sb_ + (0*16 + (w*2+0))*512); \
    acc[0][gI_] = MFMA16(aA_, wf_, acc[0][gI_]); } \
  { s8v wf_ = *(const s8v*)(sb_ + (0*16 + (w*2+1))*512); \
    acc[1][gI_] = MFMA16(aA_, wf_, acc[1][gI_]); } \
  { s8v wf_ = *(const s8v*)(sb_ + (1*16 + (w*2+0))*512); \
    acc[0][gI_] = MFMA16(aB_, wf_, acc[0][gI_]); } \
  { s8v wf_ = *(const s8v*)(sb_ + (1*16 + (w*2+1))*512); \
    acc[1][gI_] = MFMA16(aB_, wf_, acc[1][gI_]); } \
}while(0)

__global__ __launch_bounds__(TPB, 1)
void traj_mfma(const float* __restrict__ enc,   // B x 128
               const float* __restrict__ pos0,  // B x 2
               const float* __restrict__ ctx,   // B x 128
               const float* __restrict__ Wh,    // 512 x 128
               const float* __restrict__ bh,
               const float* __restrict__ Wc,
               const float* __restrict__ bc,
               const float* __restrict__ Wih0,  // 1024 x 130
               const float* __restrict__ bih0,
               const float* __restrict__ bhh0,
               const float* __restrict__ bih1,
               const float* __restrict__ bhh1,
               const float* __restrict__ Wp2,   // 2 x 64
               const float* __restrict__ bp1,
               const float* __restrict__ bp2,
               const unsigned short* __restrict__ wsW,
               float* __restrict__ out)         // B x 45 x 2
{
  __shared__ unsigned short sh_stage[3*16384]; // 96KB rotation (init: sh_x overlay)
  __shared__ unsigned short sh_gx[BB*1024];    // 32KB: ct fp32 (init) then gctx bf16
  __shared__ unsigned short sh_h0u[BB*HN];     // 8KB bf16 swizzled
  __shared__ unsigned short sh_h1u[BB*HN];     // 8KB
  __shared__ float sh_pos[BB][2];
  __shared__ float sh_red[4][BB][2];

  const int tid  = threadIdx.x;
  const int gb0  = blockIdx.x * BB;
  const int lane = tid & 63;
  const int w    = tid >> 6;        // 8 waves
  const int col  = lane & 15;
  const int hi   = lane >> 4;

  float* sh_xf = (float*)sh_stage;  // 8KB input staging overlay (init only)

  // ---- stage encoder_feat + pos ----
  {
    const float4* src = (const float4*)(enc + (size_t)gb0*DM);
    ((float4*)sh_xf)[tid] = src[tid];
  }
  if (tid < BB*2) ((float*)sh_pos)[tid] = pos0[(size_t)gb0*2 + tid];
  __syncthreads();

  // ---- h/c init: thread r computes h_all/c_all row r (fp32) ----
  {
    float* ctF = (float*)sh_gx;   // ct0 [16][256] | ct1 [16][256] (32KB)
    const int r = tid;
    float ah[BB], ac[BB];
    #pragma unroll
    for (int b=0;b<BB;b++){ ah[b]=0.f; ac[b]=0.f; }
    const float4* whr = (const float4*)(Wh + (size_t)r*DM);
    const float4* wcr = (const float4*)(Wc + (size_t)r*DM);
    #pragma nounroll
    for (int kk=0; kk<DM/4; kk++){
      float4 w0 = whr[kk], w1 = wcr[kk];
      #pragma unroll
      for (int b=0;b<BB;b++){
        float4 x = *(const float4*)&sh_xf[b*DM + kk*4];
        ah[b] += w0.x*x.x + w0.y*x.y + w0.z*x.z + w0.w*x.w;
        ac[b] += w1.x*x.x + w1.y*x.y + w1.z*x.z + w1.w*x.w;
      }
    }
    float bhv = bh[r], bcv = bc[r];
    if (r < HN){
      #pragma unroll
      for (int b=0;b<BB;b++){
        write_h(sh_h0u, b, r, ah[b] + bhv);
        ctF[(size_t)b*HN + r] = ac[b] + bcv;
      }
    } else {
      #pragma unroll
      for (int b=0;b<BB;b++){
        write_h(sh_h1u, b, r-HN, ah[b] + bhv);
        ctF[4096 + (size_t)b*HN + (r-HN)] = ac[b] + bcv;
      }
    }
  }
  __syncthreads();

  // ---- hoist c-state to regs ----
  float c0r[2][4], c1r[2][4];
  {
    const float* ctF = (const float*)sh_gx;
    #pragma unroll
    for (int m=0;m<2;m++){
      int uu = (w*2+m)*16 + col;
      #pragma unroll
      for (int q=0;q<4;q++){
        int b = hi*4+q;
        c0r[m][q] = ctF[(size_t)b*HN + uu];
        c1r[m][q] = ctF[4096 + (size_t)b*HN + uu];
      }
    }
  }
  __syncthreads();   // ct region free

  // ---- stage context ----
  {
    const float4* src = (const float4*)(ctx + (size_t)gb0*DM);
    ((float4*)sh_xf)[tid] = src[tid];
  }
  __syncthreads();

  // ---- gates_ctx -> bf16 LDS [16][1024] (persistent in sh_gx) ----
  {
    float a0[BB], a1[BB];
    #pragma unroll
    for (int b=0;b<BB;b++){ a0[b]=0.f; a1[b]=0.f; }
    const float2* wr0 = (const float2*)(Wih0 + (size_t)tid*130 + 2);
    const float2* wr1 = (const float2*)(Wih0 + (size_t)(tid+512)*130 + 2);
    #pragma nounroll
    for (int kk=0; kk<DM/2; kk++){
      float2 w0 = wr0[kk], w1 = wr1[kk];
      #pragma unroll
      for (int b=0;b<BB;b++){
        float2 x = *(const float2*)&sh_xf[b*DM + kk*2];
        a0[b] += w0.x*x.x + w0.y*x.y;
        a1[b] += w1.x*x.x + w1.y*x.y;
      }
    }
    float cb0 = bih0[tid]     + bhh0[tid];
    float cb1 = bih0[tid+512] + bhh0[tid+512];
    __syncthreads();   // everyone done reading sh_xf before gx write? (gx != sh_xf; safe but keep order)
    #pragma unroll
    for (int b=0;b<BB;b++){
      sh_gx[(size_t)b*1024 + tid]       = f2bf(a0[b] + cb0);
      sh_gx[(size_t)b*1024 + tid + 512] = f2bf(a1[b] + cb1);
    }
  }

  // ---- per-lane constants ----
  float wpr[2][4][2]; float b1r[2][4];
  #pragma unroll
  for (int m=0;m<2;m++){
    int uu = (w*2+m)*16 + col;
    #pragma unroll
    for (int g=0;g<4;g++){
      int j = (g<<8) + uu;
      wpr[m][g][0] = Wih0[(size_t)j*130 + 0];
      wpr[m][g][1] = Wih0[(size_t)j*130 + 1];
      b1r[m][g]    = bih1[j] + bhh1[j];
    }
  }
  const float bp1p = bp1[(w&3)*16 + col];
  const float w20  = Wp2[(w&3)*16 + col];
  const float w21  = Wp2[64 + (w&3)*16 + col];
  const float bp20 = bp2[0], bp21 = bp2[1];
  const unsigned short* wTp = wsW + 786432 + lane*8;   // Wp1 tiles
  __syncthreads();   // gctx visible; sh_stage free for rotation

  // ---- prologue: stage chunks 0,1 ----
  STAGE(0, 0);
  STAGE(1, 1);

  // ================= 45-step rollout =================
  #pragma nounroll
  for (int t=0; t<NSTEP; t++){
    // ---- layer0 acc init: gctx + pos ----
    f32x4 acc[2][4];
    #pragma unroll
    for (int m=0;m<2;m++){
      const int uu = (w*2+m)*16 + col;
      #pragma unroll
      for (int q=0;q<4;q++){
        float2 pp = *(const float2*)&sh_pos[hi*4+q][0];
        #pragma unroll
        for (int g=0;g<4;g++)
          acc[m][g][q] = bf2f(sh_gx[(size_t)(hi*4+q)*1024 + (g<<8) + uu])
                       + pp.x*wpr[m][g][0] + pp.y*wpr[m][g][1];
      }
    }

    // ---- Whh0 chunks 0..15 (A = h0 old) ----
    #pragma unroll
    for (int cl=0; cl<16; cl++){ CHUNK(cl, 0, sh_h0u); }
    __syncthreads();   // all h0-old reads done (drains in-flight stages 16,17)

    // ---- cell0 ----
    #pragma unroll
    for (int m=0;m<2;m++){
      int uu = (w*2+m)*16 + col;
      #pragma unroll
      for (int q=0;q<4;q++){
        float iv = sigm(acc[m][0][q]), fv = sigm(acc[m][1][q]);
        float gv = tanhx(acc[m][2][q]), ov = sigm(acc[m][3][q]);
        float cv = fv*c0r[m][q] + iv*gv;
        c0r[m][q] = cv;
        write_h(sh_h0u, hi*4+q, uu, ov*tanhx(cv));
      }
    }
    __syncthreads();   // new h0 visible

    // ---- layer1 acc init ----
    #pragma unroll
    for (int m=0;m<2;m++)
      #pragma unroll
      for (int g=0;g<4;g++)
        #pragma unroll
        for (int q=0;q<4;q++)
          acc[m][g][q] = b1r[m][g];

    // ---- Wih1 chunks 16..31 (A = h0 new), Whh1 chunks 32..47 (A = h1 old) ----
    #pragma unroll
    for (int cl=0; cl<16; cl++){ CHUNK(cl, 1, sh_h0u); }
    #pragma unroll
    for (int cl=0; cl<16; cl++){ CHUNK(cl, 2, sh_h1u); }
    __syncthreads();   // all h1-old reads done (drains wrapped stages 0,1)

    // ---- cell1 ----
    #pragma unroll
    for (int m=0;m<2;m++){
      int uu = (w*2+m)*16 + col;
      #pragma unroll
      for (int q=0;q<4;q++){
        float iv = sigm(acc[m][0][q]), fv = sigm(acc[m][1][q]);
        float gv = tanhx(acc[m][2][q]), ov = sigm(acc[m][3][q]);
        float cv = fv*c1r[m][q] + iv*gv;
        c1r[m][q] = cv;
        write_h(sh_h1u, hi*4+q, uu, ov*tanhx(cv));
      }
    }
    __syncthreads();   // new h1 visible

    // ---- head (waves 0..3; p-unit = (w&3)*16+col), Wp1 direct from L2 ----
    if (w < 4){
      f32x4 hp = {bp1p, bp1p, bp1p, bp1p};
      #pragma unroll
      for (int kt=0;kt<8;kt++){
        s8v a1n = read_afrag(sh_h1u, col, hi, kt);
        s8v wfp = *(const s8v*)(wTp + (size_t)((w&3)*8+kt)*512);
        hp = MFMA16(a1n, wfp, hp);
      }
      #pragma unroll
      for (int q=0;q<4;q++){
        float r  = fmaxf(hp[q], 0.f);
        float s0 = r*w20, s1 = r*w21;
        #pragma unroll
        for (int off=1; off<16; off<<=1){
          s0 += __shfl_xor(s0, off, 64);
          s1 += __shfl_xor(s1, off, 64);
        }
        if (col == 0){ sh_red[w][hi*4+q][0] = s0; sh_red[w][hi*4+q][1] = s1; }
      }
    }
    __syncthreads();   // sh_red complete

    // ---- combine, update pos, write out ----
    if (tid < BB*2){
      int b = tid >> 1, d = tid & 1;
      float s = sh_red[0][b][d] + sh_red[1][b][d] + sh_red[2][b][d] + sh_red[3][b][d]
              + (d ? bp21 : bp20);
      float np = sh_pos[b][d] + s;
      sh_pos[b][d] = np;
      out[((size_t)(gb0+b)*NSTEP + t)*2 + d] = np;
    }
    __syncthreads();   // pos stable for next step
  }
}

extern "C" void kernel_launch(void* const* d_in, const int* in_sizes, int n_in,
                              void* d_out, int out_size, void* d_ws, size_t ws_size,
                              hipStream_t stream) {
  const float* enc  = (const float*)d_in[0];
  const float* pos0 = (const float*)d_in[1];
  const float* ctx  = (const float*)d_in[2];
  const float* Wh   = (const float*)d_in[3];
  const float* bh   = (const float*)d_in[4];
  const float* Wc   = (const float*)d_in[5];
  const float* bc   = (const float*)d_in[6];
  const float* Wih0 = (const float*)d_in[7];
  const float* Whh0 = (const float*)d_in[8];
  const float* bih0 = (const float*)d_in[9];
  const float* bhh0 = (const float*)d_in[10];
  const float* Wih1 = (const float*)d_in[11];
  const float* Whh1 = (const float*)d_in[12];
  const float* bih1 = (const float*)d_in[13];
  const float* bhh1 = (const float*)d_in[14];
  const float* Wp1  = (const float*)d_in[15];
  const float* bp1  = (const float*)d_in[16];
  const float* Wp2  = (const float*)d_in[17];
  const float* bp2  = (const float*)d_in[18];
  float* out = (float*)d_out;
  unsigned short* wsW = (unsigned short*)d_ws;

  hipLaunchKernelGGL(repack, dim3(392), dim3(256), 0, stream,
                     Whh0, Wih1, Whh1, Wp1, wsW);

  const int B = 4096;
  hipLaunchKernelGGL(traj_mfma, dim3(B / BB), dim3(TPB), 0, stream,
                     enc, pos0, ctx, Wh, bh, Wc, bc, Wih0, bih0, bhh0,
                     bih1, bhh1, Wp2, bp1, bp2, wsW, out);
}